// Round 1
// baseline (1301.852 us; speedup 1.0000x reference)
//
#include <hip/hip_runtime.h>
#include <hip/hip_bf16.h>

// ---------------- problem constants ----------------
#define T_TOK 1024
#define H_DIM 2048
#define E_NUM 64
#define I_DIM 768
#define TOPK  8
#define NROWS (T_TOK * TOPK)   // 8192 (token,expert) rows total

// GEMM tiling
#define MCAP  192              // max rows per expert (128 + 5.7 sigma)
#define PITCH 40               // LDS row pitch in bf16 elems (32 + 8 pad; 80B, b128-aligned, 2-way-free banks)
#define BK    32

// workspace layout (bytes)
#define WS_COUNTS   0
#define WS_FILL     256
#define WS_OFFS     512
#define WS_TOPK_IDS 1024
#define WS_TOPK_W   33792
#define WS_TLIST    66560
#define WS_WLIST    99328
#define WS_HB       132096            // hidden bf16: 1024*2048*2 = 4 MiB
#define WS_ACT      4326400           // act bf16: 8192*768*2 = 12.6 MB  (end ~16.9 MB)

typedef float f32x4 __attribute__((ext_vector_type(4)));
typedef short s16x8 __attribute__((ext_vector_type(8)));

static __device__ __forceinline__ unsigned pack2(float a, float b) {
    __hip_bfloat162 h = __float22bfloat162_rn(float2{a, b});
    return *reinterpret_cast<unsigned*>(&h);
}
static __device__ __forceinline__ unsigned short bf16b(float a) {
    __hip_bfloat16 h = __float2bfloat16(a);
    return *reinterpret_cast<unsigned short*>(&h);
}

// ---------------- hidden fp32 -> bf16 ----------------
__global__ __launch_bounds__(256) void k_convert(const float* __restrict__ x,
                                                 unsigned short* __restrict__ hb) {
    int i = (blockIdx.x * 256 + threadIdx.x) * 4;     // 2048 blocks * 1024 elems = 2M exact
    float4 v = *reinterpret_cast<const float4*>(x + i);
    unsigned lo = pack2(v.x, v.y), hi = pack2(v.z, v.w);
    uint2 p; p.x = lo; p.y = hi;
    *reinterpret_cast<uint2*>(hb + i) = p;
}

// ---------------- router: logits -> top8 -> renorm weights ----------------
// 8 tokens per block; threads = (e in 0..63) x (j in 0..3 h-chunks of 512)
__global__ __launch_bounds__(256) void k_router(const float* __restrict__ x,
                                                const float* __restrict__ gw,
                                                int* __restrict__ counts,
                                                int* __restrict__ topk_ids,
                                                float* __restrict__ topk_w) {
    __shared__ float part[4][8][64];
    __shared__ float lgt[64][8];
    int tid = threadIdx.x;
    int e = tid & 63, j = tid >> 6;
    int t0 = blockIdx.x * 8;

    float acc[8];
#pragma unroll
    for (int t = 0; t < 8; t++) acc[t] = 0.0f;

    const float* gp = gw + (size_t)e * H_DIM + j * 512;
    const float* xp = x + (size_t)t0 * H_DIM + j * 512;
    for (int h = 0; h < 512; h += 4) {
        float4 g = *reinterpret_cast<const float4*>(gp + h);
#pragma unroll
        for (int t = 0; t < 8; t++) {
            float4 xv = *reinterpret_cast<const float4*>(xp + (size_t)t * H_DIM + h);
            acc[t] += g.x * xv.x + g.y * xv.y + g.z * xv.z + g.w * xv.w;
        }
    }
#pragma unroll
    for (int t = 0; t < 8; t++) part[j][t][e] = acc[t];
    __syncthreads();
    for (int s = tid; s < 512; s += 256) {
        int ee = s & 63, t = s >> 6;
        lgt[ee][t] = part[0][t][ee] + part[1][t][ee] + part[2][t][ee] + part[3][t][ee];
    }
    __syncthreads();
    if (tid < 8) {
        int t = tid;
        int ids[8]; float ws[8];
#pragma unroll
        for (int k = 0; k < 8; k++) {
            float best = -3.0e38f; int bi = 0;
            for (int e2 = 0; e2 < 64; e2++) {
                float v = lgt[e2][t];
                if (v > best) { best = v; bi = e2; }
            }
            ids[k] = bi; ws[k] = best;
            lgt[bi][t] = -3.0e38f;
        }
        // renormalized top-k softmax weights: exp(l_i)/sum_top8 exp(l_j)
        float m = ws[0], s = 0.0f;
#pragma unroll
        for (int k = 0; k < 8; k++) { ws[k] = expf(ws[k] - m); s += ws[k]; }
        float inv = 1.0f / s;
#pragma unroll
        for (int k = 0; k < 8; k++) {
            topk_ids[(t0 + t) * TOPK + k] = ids[k];
            topk_w[(t0 + t) * TOPK + k] = ws[k] * inv;
            atomicAdd(&counts[ids[k]], 1);
        }
    }
}

// ---------------- exclusive scan of counts ----------------
__global__ void k_scan(const int* __restrict__ counts, int* __restrict__ offsets) {
    if (threadIdx.x == 0) {
        int s = 0;
        for (int e = 0; e < E_NUM; e++) { offsets[e] = s; s += counts[e]; }
        offsets[E_NUM] = s;
    }
}

// ---------------- scatter (token,weight) into per-expert compact lists ----------------
__global__ __launch_bounds__(256) void k_scatter(const int* __restrict__ topk_ids,
                                                 const float* __restrict__ topk_w,
                                                 const int* __restrict__ offsets,
                                                 int* __restrict__ fill,
                                                 int* __restrict__ token_list,
                                                 float* __restrict__ weight_list) {
    int g = blockIdx.x * 256 + threadIdx.x;
    if (g >= NROWS) return;
    int e = topk_ids[g];
    float w = topk_w[g];
    int pos = offsets[e] + atomicAdd(&fill[e], 1);
    token_list[pos] = g >> 3;
    weight_list[pos] = w;
}

// ---------------- gate+up GEMM + SwiGLU epilogue ----------------
// grid (12 n-tiles of 64 over I, 64 experts), 256 threads (4 waves)
__global__ __launch_bounds__(256) void k_gateup(
    const float* __restrict__ wg, const float* __restrict__ wu,
    const unsigned short* __restrict__ hb,
    const int* __restrict__ token_list, const float* __restrict__ weight_list,
    const int* __restrict__ offsets, unsigned short* __restrict__ act) {
    __shared__ unsigned short As[MCAP * PITCH];     // 15360 B
    __shared__ unsigned short Bs[2 * 64 * PITCH];   // 10240 B (transposed: [mat][n][k])
    __shared__ float wrow[MCAP];

    int e = blockIdx.y;
    int n0 = blockIdx.x * 64;
    int off = offsets[e];
    int M = offsets[e + 1] - off;
    if (M <= 0) return;
    if (M > MCAP) M = MCAP;      // safety (P ~ 4e-7)
    int nmf = (M + 15) >> 4;
    int tid = threadIdx.x;

    // zero-fill A pad rows [M, nmf*16) once (single-buffered LDS, valid rows rewritten each step)
    for (int idx = M * PITCH + tid; idx < nmf * 16 * PITCH; idx += 256) As[idx] = 0;
    if (tid < MCAP) wrow[tid] = (tid < M) ? weight_list[off + tid] : 0.0f;

    // A loader: 64 rows/pass, 4 threads per row (8 bf16 = 16B each)
    const unsigned short* aptr[3]; bool aval[3]; int arow[3];
#pragma unroll
    for (int p = 0; p < 3; p++) {
        int row = p * 64 + (tid >> 2);
        arow[p] = row; aval[p] = (row < M);
        aptr[p] = aval[p] ? (hb + (size_t)token_list[off + row] * H_DIM + (tid & 3) * 8) : hb;
    }
    // B loader: mat = tid>>7, 128 threads per matrix; n-quad x k-pair
    int mat = tid >> 7, iw = tid & 127, n4 = iw & 15, kp = iw >> 4;
    const float* wsrc = (mat ? wu : wg) + (size_t)e * H_DIM * I_DIM + n0 + n4 * 4;
    unsigned short* bdst = Bs + (mat * 64 + n4 * 4) * PITCH;

    int w = tid >> 6, lane = tid & 63, wm = w >> 1, wn = w & 1;
    int mrow = lane & 15, quad = lane >> 4;

    f32x4 acc[6][2][2] = {};

    for (int k0 = 0; k0 < H_DIM; k0 += BK) {
        // stage A (bf16 direct)
#pragma unroll
        for (int p = 0; p < 3; p++)
            if (aval[p]) {
                uint4 v = *reinterpret_cast<const uint4*>(aptr[p] + k0);
                *reinterpret_cast<uint4*>(As + arow[p] * PITCH + (tid & 3) * 8) = v;
            }
        // stage B: fp32 -> bf16, transpose into [n][k]
#pragma unroll
        for (int pass = 0; pass < 2; pass++) {
            int kk = 2 * kp + 16 * pass;
            const float* src = wsrc + (size_t)(k0 + kk) * I_DIM;
            float4 r0 = *reinterpret_cast<const float4*>(src);
            float4 r1 = *reinterpret_cast<const float4*>(src + I_DIM);
            unsigned short* d = bdst + kk;
            *reinterpret_cast<unsigned*>(d + 0 * PITCH) = pack2(r0.x, r1.x);
            *reinterpret_cast<unsigned*>(d + 1 * PITCH) = pack2(r0.y, r1.y);
            *reinterpret_cast<unsigned*>(d + 2 * PITCH) = pack2(r0.z, r1.z);
            *reinterpret_cast<unsigned*>(d + 3 * PITCH) = pack2(r0.w, r1.w);
        }
        __syncthreads();
        // compute
        s16x8 bf[2][2];
#pragma unroll
        for (int m2 = 0; m2 < 2; m2++)
#pragma unroll
            for (int nf = 0; nf < 2; nf++)
                bf[m2][nf] = *reinterpret_cast<const s16x8*>(
                    Bs + (m2 * 64 + wn * 32 + nf * 16 + mrow) * PITCH + quad * 8);
#pragma unroll
        for (int i = 0; i < 6; i++) {
            int mf = 2 * i + wm;
            if (mf < nmf) {
                s16x8 af = *reinterpret_cast<const s16x8*>(As + (mf * 16 + mrow) * PITCH + quad * 8);
#pragma unroll
                for (int m2 = 0; m2 < 2; m2++)
#pragma unroll
                    for (int nf = 0; nf < 2; nf++)
                        acc[i][nf][m2] = __builtin_amdgcn_mfma_f32_16x16x32_bf16(
                            af, bf[m2][nf], acc[i][nf][m2], 0, 0, 0);
            }
        }
        __syncthreads();
    }
    // epilogue: act = silu(g) * u * routing_w  -> bf16
#pragma unroll
    for (int i = 0; i < 6; i++) {
        int mf = 2 * i + wm;
        if (mf >= nmf) continue;
#pragma unroll
        for (int nf = 0; nf < 2; nf++) {
#pragma unroll
            for (int r = 0; r < 4; r++) {
                int row = mf * 16 + quad * 4 + r;
                if (row < M) {
                    float g = acc[i][nf][0][r];
                    float u = acc[i][nf][1][r];
                    float a = (g / (1.0f + expf(-g))) * u * wrow[row];
                    act[(size_t)(off + row) * I_DIM + n0 + wn * 32 + nf * 16 + mrow] = bf16b(a);
                }
            }
        }
    }
}

// ---------------- down GEMM + atomic scatter-add ----------------
// grid (16 n-tiles of 128 over H, 64 experts), 256 threads
__global__ __launch_bounds__(256) void k_down(
    const float* __restrict__ wd, const unsigned short* __restrict__ act,
    const int* __restrict__ token_list, const int* __restrict__ offsets,
    float* __restrict__ out) {
    __shared__ unsigned short As[MCAP * PITCH];   // 15360 B
    __shared__ unsigned short Bs[128 * PITCH];    // 10240 B
    __shared__ int toks[MCAP];

    int e = blockIdx.y;
    int n0 = blockIdx.x * 128;
    int off = offsets[e];
    int M = offsets[e + 1] - off;
    if (M <= 0) return;
    if (M > MCAP) M = MCAP;
    int nmf = (M + 15) >> 4;
    int tid = threadIdx.x;

    for (int idx = M * PITCH + tid; idx < nmf * 16 * PITCH; idx += 256) As[idx] = 0;
    if (tid < MCAP) toks[tid] = (tid < M) ? token_list[off + tid] : 0;

    const unsigned short* aptr[3]; bool aval[3]; int arow[3];
#pragma unroll
    for (int p = 0; p < 3; p++) {
        int row = p * 64 + (tid >> 2);
        arow[p] = row; aval[p] = (row < M);
        aptr[p] = aval[p] ? (act + (size_t)(off + row) * I_DIM + (tid & 3) * 8) : act;
    }
    int n4 = tid & 31, kp = tid >> 5;
    const float* wsrc = wd + (size_t)e * I_DIM * H_DIM + n0 + n4 * 4;
    unsigned short* bdst = Bs + (n4 * 4) * PITCH;

    int w = tid >> 6, lane = tid & 63, wm = w >> 1, wn = w & 1;
    int mrow = lane & 15, quad = lane >> 4;

    f32x4 acc[6][4] = {};

    for (int k0 = 0; k0 < I_DIM; k0 += BK) {
#pragma unroll
        for (int p = 0; p < 3; p++)
            if (aval[p]) {
                uint4 v = *reinterpret_cast<const uint4*>(aptr[p] + k0);
                *reinterpret_cast<uint4*>(As + arow[p] * PITCH + (tid & 3) * 8) = v;
            }
#pragma unroll
        for (int pass = 0; pass < 2; pass++) {
            int kk = 2 * kp + 16 * pass;
            const float* src = wsrc + (size_t)(k0 + kk) * H_DIM;
            float4 r0 = *reinterpret_cast<const float4*>(src);
            float4 r1 = *reinterpret_cast<const float4*>(src + H_DIM);
            unsigned short* d = bdst + kk;
            *reinterpret_cast<unsigned*>(d + 0 * PITCH) = pack2(r0.x, r1.x);
            *reinterpret_cast<unsigned*>(d + 1 * PITCH) = pack2(r0.y, r1.y);
            *reinterpret_cast<unsigned*>(d + 2 * PITCH) = pack2(r0.z, r1.z);
            *reinterpret_cast<unsigned*>(d + 3 * PITCH) = pack2(r0.w, r1.w);
        }
        __syncthreads();
        s16x8 bf[4];
#pragma unroll
        for (int nf = 0; nf < 4; nf++)
            bf[nf] = *reinterpret_cast<const s16x8*>(
                Bs + (wn * 64 + nf * 16 + mrow) * PITCH + quad * 8);
#pragma unroll
        for (int i = 0; i < 6; i++) {
            int mf = 2 * i + wm;
            if (mf < nmf) {
                s16x8 af = *reinterpret_cast<const s16x8*>(As + (mf * 16 + mrow) * PITCH + quad * 8);
#pragma unroll
                for (int nf = 0; nf < 4; nf++)
                    acc[i][nf] = __builtin_amdgcn_mfma_f32_16x16x32_bf16(af, bf[nf], acc[i][nf], 0, 0, 0);
            }
        }
        __syncthreads();
    }
#pragma unroll
    for (int i = 0; i < 6; i++) {
        int mf = 2 * i + wm;
        if (mf >= nmf) continue;
#pragma unroll
        for (int nf = 0; nf < 4; nf++) {
#pragma unroll
            for (int r = 0; r < 4; r++) {
                int row = mf * 16 + quad * 4 + r;
                if (row < M) {
                    atomicAdd(&out[(size_t)toks[row] * H_DIM + n0 + wn * 64 + nf * 16 + mrow],
                              acc[i][nf][r]);
                }
            }
        }
    }
}

extern "C" void kernel_launch(void* const* d_in, const int* in_sizes, int n_in,
                              void* d_out, int out_size, void* d_ws, size_t ws_size,
                              hipStream_t stream) {
    (void)in_sizes; (void)n_in; (void)ws_size;
    const float* x  = (const float*)d_in[0];   // [1024, 2048]
    const float* gw = (const float*)d_in[1];   // [64, 2048]
    const float* wg = (const float*)d_in[2];   // [64, 2048, 768]
    const float* wu = (const float*)d_in[3];   // [64, 2048, 768]
    const float* wd = (const float*)d_in[4];   // [64, 768, 2048]
    float* out = (float*)d_out;

    char* ws = (char*)d_ws;
    int* counts        = (int*)(ws + WS_COUNTS);
    int* fill          = (int*)(ws + WS_FILL);
    int* offsets       = (int*)(ws + WS_OFFS);
    int* topk_ids      = (int*)(ws + WS_TOPK_IDS);
    float* topk_w      = (float*)(ws + WS_TOPK_W);
    int* token_list    = (int*)(ws + WS_TLIST);
    float* weight_list = (float*)(ws + WS_WLIST);
    unsigned short* hb  = (unsigned short*)(ws + WS_HB);
    unsigned short* act = (unsigned short*)(ws + WS_ACT);

    hipMemsetAsync(ws, 0, 1024, stream);                        // counts + fill + offsets
    hipMemsetAsync(d_out, 0, (size_t)out_size * 4, stream);     // out accumulators

    k_convert<<<2048, 256, 0, stream>>>(x, hb);
    k_router<<<128, 256, 0, stream>>>(x, gw, counts, topk_ids, topk_w);
    k_scan<<<1, 64, 0, stream>>>(counts, offsets);
    k_scatter<<<32, 256, 0, stream>>>(topk_ids, topk_w, offsets, fill, token_list, weight_list);
    k_gateup<<<dim3(12, 64), 256, 0, stream>>>(wg, wu, hb, token_list, weight_list, offsets, act);
    k_down<<<dim3(16, 64), 256, 0, stream>>>(wd, act, token_list, offsets, out);
}